// Round 15
// baseline (162.334 us; speedup 1.0000x reference)
//
#include <hip/hip_runtime.h>
#include <hip/hip_bf16.h>

typedef __hip_bfloat16 bf16;
typedef __attribute__((ext_vector_type(8))) short short8;   // 8 bf16, 4 VGPRs
typedef __attribute__((ext_vector_type(4))) short shortx4;  // 4 bf16 (HIP owns "short4")
typedef __attribute__((ext_vector_type(4))) float floatx4;  // MFMA acc

// B=8, T=8192, D=64, M=256, chunk L=64, NCHUNK=1024, NTOK=65536
#define NEED_WS_BYTES 110625024ULL

__device__ __forceinline__ float b2f(bf16 x) { return __bfloat162float(x); }
__device__ __forceinline__ bf16  f2b(float x) { return __float2bfloat16(x); }
__device__ __forceinline__ float bflo(unsigned u) { return __uint_as_float(u << 16); }
__device__ __forceinline__ float bfhi(unsigned u) { return __uint_as_float(u & 0xffff0000u); }

// dtype-dispatched input load: isf32 ? f32 : bf16
__device__ __forceinline__ float ldin(const void* p, size_t i, int isf32) {
  return isf32 ? ((const float*)p)[i] : b2f(((const bf16*)p)[i]);
}

// f32 -> bf16 bits
__device__ __forceinline__ short tob(float f) {
  bf16 h = f2b(f);
  return *reinterpret_cast<short*>(&h);
}
// f32 -> bf16 bits of (f * 0.125)
__device__ __forceinline__ short sb(float f) { return tob(f * 0.125f); }
// bf16 bits -> bf16 bits of (x * 0.125) (exact exponent shift)
__device__ __forceinline__ short scale_b(short u) {
  return tob(__uint_as_float(((unsigned)(unsigned short)u) << 16) * 0.125f);
}

// inline dtype detect on q's first 8KB (R13 LESSON: run ONCE in tiny k_omega).
__device__ __forceinline__ int detect_f32(const void* q, int tid, int* cntp) {
  if (tid == 0) *cntp = 0;
  __syncthreads();
  const unsigned short* u = (const unsigned short*)q;
  int c = 0;
  for (int e = tid; e < 2048; e += 256) {
    unsigned short w = u[2 * e];
    int ex = (w >> 7) & 0xFF;
    if ((w & 0x7FFF) != 0 && (ex < 110 || ex > 140)) c++;
  }
  atomicAdd(cntp, c);
  __syncthreads();
  return (*cntp > 512) ? 1 : 0;
}

// ---- k_omega: detect + omega->bf16 buffer; block 0 publishes flag ----------
__global__ __launch_bounds__(256) void k_omega(const void* __restrict__ q,
                                               const void* __restrict__ omega,
                                               bf16* __restrict__ omb,
                                               int* __restrict__ flag) {
  __shared__ int cnt;
  int tid = threadIdx.x;
  int isf32 = detect_f32(q, tid, &cnt);
  if (blockIdx.x == 0 && tid == 0) *flag = isf32;
  int e = blockIdx.x * 256 + tid;
  omb[e] = f2b(ldin(omega, e, isf32));
}

// ---- shared phi helpers ----------------------------------------------------
// Layouts (m89/m91-verified): A[m=lane&15][k=quad*8+j], B[n=lane&15][k=quad*8+j],
// C: col=lane&15 (n-dim), row=quad*4+reg (m-dim).
__device__ __forceinline__ void phi_load_a(const void* src, size_t row, int quad,
                                           int isf32, short8& a0, short8& a1) {
  if (isf32) {
    const float* xr = (const float*)src + row * 64;
    float4 f0 = *reinterpret_cast<const float4*>(xr + quad * 8);
    float4 f1 = *reinterpret_cast<const float4*>(xr + quad * 8 + 4);
    float4 f2 = *reinterpret_cast<const float4*>(xr + 32 + quad * 8);
    float4 f3 = *reinterpret_cast<const float4*>(xr + 32 + quad * 8 + 4);
    a0[0] = sb(f0.x); a0[1] = sb(f0.y); a0[2] = sb(f0.z); a0[3] = sb(f0.w);
    a0[4] = sb(f1.x); a0[5] = sb(f1.y); a0[6] = sb(f1.z); a0[7] = sb(f1.w);
    a1[0] = sb(f2.x); a1[1] = sb(f2.y); a1[2] = sb(f2.z); a1[3] = sb(f2.w);
    a1[4] = sb(f3.x); a1[5] = sb(f3.y); a1[6] = sb(f3.z); a1[7] = sb(f3.w);
  } else {
    const short* xr = (const short*)src + row * 64;
    short8 r0 = *reinterpret_cast<const short8*>(xr + quad * 8);
    short8 r1 = *reinterpret_cast<const short8*>(xr + 32 + quad * 8);
    #pragma unroll
    for (int j = 0; j < 8; ++j) { a0[j] = scale_b(r0[j]); a1[j] = scale_b(r1[j]); }
  }
}

// ---- omega staged in LDS [256 rows][8 segs of 16B], XOR-swizzled -----------
__device__ __forceinline__ void stage_omb_lds(const bf16* __restrict__ omb,
                                              short* __restrict__ lds, int tid) {
  const short* src = (const short*)omb;
  #pragma unroll
  for (int it = 0; it < 8; ++it) {
    int seg = it * 256 + tid;          // [0,2048)
    int row = seg >> 3, s = seg & 7;
    *reinterpret_cast<short8*>(&lds[row * 64 + (s ^ (row & 7)) * 8]) =
        *reinterpret_cast<const short8*>(src + row * 64 + s * 8);
  }
}

// phi MFMA with B-frags from swizzled LDS omega (bit-identical values).
__device__ __forceinline__ void phi_mfma_lds(const short* __restrict__ oml,
                                             int li, int quad,
                                             const short8& a0, const short8& a1,
                                             floatx4* c, float* mx) {
  int x = li & 7;
  #pragma unroll
  for (int n0 = 0; n0 < 16; ++n0) {
    const short* rp = oml + (n0 * 16 + li) * 64;
    short8 b0 = *reinterpret_cast<const short8*>(rp + (quad ^ x) * 8);
    short8 b1 = *reinterpret_cast<const short8*>(rp + ((quad + 4) ^ x) * 8);
    floatx4 acc = {0.f, 0.f, 0.f, 0.f};
    acc = __builtin_amdgcn_mfma_f32_16x16x32_bf16(a0, b0, acc, 0, 0, 0);
    acc = __builtin_amdgcn_mfma_f32_16x16x32_bf16(a1, b1, acc, 0, 0, 0);
    c[n0] = acc;
  }
  #pragma unroll
  for (int r = 0; r < 4; ++r) {
    float m = c[0][r];
    #pragma unroll
    for (int n0 = 1; n0 < 16; ++n0) m = fmaxf(m, c[n0][r]);
    mx[r] = m;
  }
  #pragma unroll
  for (int mask = 1; mask < 16; mask <<= 1) {
    #pragma unroll
    for (int r = 0; r < 4; ++r) mx[r] = fmaxf(mx[r], __shfl_xor(mx[r], mask, 64));
  }
}

// ---- k_phik (R14 config, unchanged — measured 42.8us) ----------------------
__global__ __launch_bounds__(256)
__attribute__((amdgpu_waves_per_eu(1, 4))) void k_phik(
    const void* __restrict__ k, const void* __restrict__ v,
    const bf16* __restrict__ omb, bf16* __restrict__ phiK,
    bf16* __restrict__ SlocT, float* __restrict__ zloc,
    const int* __restrict__ flag) {
  __shared__ short pkT[256 * 64];    // 32768 B  omega (phase 1) -> phiK^T
  __shared__ short vT[64 * 64];      //  8192 B  V^T bf16, XOR-swizzled

  int isf32 = *flag;
  int tid = threadIdx.x;
  size_t tok0 = (size_t)blockIdx.x * 64;
  int li = tid & 15;
  int quad = (tid >> 4) & 3;
  int w = tid >> 6;
  int m0 = w * 16;
  size_t row = tok0 + m0 + li;

  // ---- stage omega -> pkT region + V^T (bf16, swizzled) --------------------
  stage_omb_lds(omb, pkT, tid);
  #pragma unroll
  for (int it = 0; it < 16; ++it) {
    int e = it * 256 + tid;
    int tau = e >> 6, d = e & 63;
    vT[d * 64 + (((tau >> 3) ^ (d & 7)) * 8) + (tau & 7)] =
        tob(ldin(v, tok0 * 64 + e, isf32));
  }
  short8 a0, a1;
  phi_load_a(k, row, quad, isf32, a0, a1);

  __syncthreads();   // BAR_A: omega LDS ready

  // ---- phi compute (B-frags from LDS) --------------------------------------
  floatx4 c[16];
  float mx[4];
  phi_mfma_lds(pkT, li, quad, a0, a1, c, mx);

  __syncthreads();   // BAR_B: all waves done reading omega -> reuse as pkT

  // ---- exp -> phiK global scatter + swizzled pkT ---------------------------
  #pragma unroll
  for (int n0 = 0; n0 < 16; ++n0) {
    #pragma unroll
    for (int r = 0; r < 4; ++r) {
      bf16 hv = f2b(__expf(c[n0][r] - mx[r]) * 0.0625f);  // 1/sqrt(256)
      short hb = *reinterpret_cast<short*>(&hv);
      int i = n0 * 16 + li;
      int t = m0 + quad * 4 + r;
      ((short*)phiK)[(tok0 + t) * 256 + i] = hb;            // 4x32B segs/instr
      int cch = (t >> 3) ^ (i & 7);                         // XOR chunk swizzle
      pkT[i * 64 + cch * 8 + (t & 7)] = hb;
    }
  }

  __syncthreads();   // BAR_C: pkT ready

  // ---- z[i] = rowsum of pkT row i (same rounded values) --------------------
  {
    int i2 = tid;
    float zz = 0.f;
    #pragma unroll
    for (int c8 = 0; c8 < 8; ++c8) {
      short8 vv8 = *reinterpret_cast<const short8*>(
          &pkT[i2 * 64 + (c8 ^ (i2 & 7)) * 8]);
      #pragma unroll
      for (int j = 0; j < 8; ++j) zz += bflo((unsigned)(unsigned short)vv8[j]);
    }
    zloc[(size_t)blockIdx.x * 256 + i2] = zz;
  }

  // ---- S GEMM (bf16 V): wave w -> features [w*64, w*64+64), all d ----------
  int wbase = w * 64;
  floatx4 sa[4][4];
  #pragma unroll
  for (int mt = 0; mt < 4; ++mt)
    #pragma unroll
    for (int n0 = 0; n0 < 4; ++n0) sa[mt][n0] = (floatx4){0.f, 0.f, 0.f, 0.f};

  #pragma unroll
  for (int h = 0; h < 2; ++h) {
    short8 Ah[4];
    #pragma unroll
    for (int mt = 0; mt < 4; ++mt)
      Ah[mt] = *reinterpret_cast<const short8*>(
          &vT[(mt * 16 + li) * 64 + ((h * 4 + quad) ^ (li & 7)) * 8]);
    #pragma unroll
    for (int n0 = 0; n0 < 4; ++n0) {
      int crow = wbase + n0 * 16 + li;
      int cc = (h * 4 + quad) ^ (li & 7);
      short8 Bq = *reinterpret_cast<const short8*>(&pkT[crow * 64 + cc * 8]);
      #pragma unroll
      for (int mt = 0; mt < 4; ++mt)
        sa[mt][n0] =
            __builtin_amdgcn_mfma_f32_16x16x32_bf16(Ah[mt], Bq, sa[mt][n0], 0, 0, 0);
    }
  }

  // ---- store S^T (bf16) ----------------------------------------------------
  bf16* Sb = SlocT + (size_t)blockIdx.x * 16384;
  #pragma unroll
  for (int mt = 0; mt < 4; ++mt)
    #pragma unroll
    for (int n0 = 0; n0 < 4; ++n0)
      #pragma unroll
      for (int r = 0; r < 4; ++r)
        Sb[(mt * 16 + quad * 4 + r) * 256 + wbase + n0 * 16 + li] =
            f2b(sa[mt][n0][r]);
}

// ---- k_prefix (R15): S-scan vectorized to uint4 (16B/lane = 1KB/wave-req) --
// Theory: k_prefix ~35-40us for 64MB r+w (~1.7 TB/s) — 4B/lane loads at 32KB
// stride were 256B/wave requests. uint4 gives 1KB requests; 256 S-blocks x
// 256 thr x 32 loads x 16B = 32MB in flight >> BW*latency (~2.4MB).
// Same per-column f32 running-sum order -> bit-identical results.
// Blocks [0,256): S-scan (batch b = bid>>5, group g = bid&31; thread owns one
// uint4 column = 4 bf16 cols x 2 pairs; wave w scans chunks [w*32, w*32+32)).
// Blocks [256,288): z-scan (f32), unchanged scheme.
__global__ __launch_bounds__(256) void k_prefix(bf16* __restrict__ SlocT,
                                                float* __restrict__ zloc) {
  __shared__ float tot[4][64][8];
  int tid = threadIdx.x;
  int lane = tid & 63;
  int w = tid >> 6;
  if (blockIdx.x < 256) {
    int b = blockIdx.x >> 5, g = blockIdx.x & 31;
    int p4 = g * 64 + lane;                  // uint4 column [0,2048)
    uint4* base = (uint4*)(SlocT + (size_t)b * 2097152) + p4;  // +2048/chunk
    uint4 vb[32];
    #pragma unroll
    for (int j = 0; j < 32; ++j) vb[j] = base[(size_t)(w * 32 + j) * 2048];
    float t0 = 0.f, t1 = 0.f, t2 = 0.f, t3 = 0.f;
    float t4 = 0.f, t5 = 0.f, t6 = 0.f, t7 = 0.f;
    #pragma unroll
    for (int j = 0; j < 32; ++j) {
      t0 += bflo(vb[j].x); t1 += bfhi(vb[j].x);
      t2 += bflo(vb[j].y); t3 += bfhi(vb[j].y);
      t4 += bflo(vb[j].z); t5 += bfhi(vb[j].z);
      t6 += bflo(vb[j].w); t7 += bfhi(vb[j].w);
    }
    tot[w][lane][0] = t0; tot[w][lane][1] = t1;
    tot[w][lane][2] = t2; tot[w][lane][3] = t3;
    tot[w][lane][4] = t4; tot[w][lane][5] = t5;
    tot[w][lane][6] = t6; tot[w][lane][7] = t7;
    __syncthreads();
    float r0 = 0.f, r1 = 0.f, r2 = 0.f, r3 = 0.f;
    float r4 = 0.f, r5 = 0.f, r6 = 0.f, r7 = 0.f;
    for (int w2 = 0; w2 < w; ++w2) {          // wave-uniform trip count
      r0 += tot[w2][lane][0]; r1 += tot[w2][lane][1];
      r2 += tot[w2][lane][2]; r3 += tot[w2][lane][3];
      r4 += tot[w2][lane][4]; r5 += tot[w2][lane][5];
      r6 += tot[w2][lane][6]; r7 += tot[w2][lane][7];
    }
    #pragma unroll
    for (int j = 0; j < 32; ++j) {
      uint4 u = vb[j];
      uint4 pw;
      pw.x = ((unsigned)(unsigned short)tob(r0)) |
             (((unsigned)(unsigned short)tob(r1)) << 16);
      pw.y = ((unsigned)(unsigned short)tob(r2)) |
             (((unsigned)(unsigned short)tob(r3)) << 16);
      pw.z = ((unsigned)(unsigned short)tob(r4)) |
             (((unsigned)(unsigned short)tob(r5)) << 16);
      pw.w = ((unsigned)(unsigned short)tob(r6)) |
             (((unsigned)(unsigned short)tob(r7)) << 16);
      base[(size_t)(w * 32 + j) * 2048] = pw;
      r0 += bflo(u.x); r1 += bfhi(u.x);
      r2 += bflo(u.y); r3 += bfhi(u.y);
      r4 += bflo(u.z); r5 += bfhi(u.z);
      r6 += bflo(u.w); r7 += bfhi(u.w);
    }
  } else {
    int idx = blockIdx.x - 256;               // [0,32)
    int b = idx >> 2, ig = idx & 3;
    int i = ig * 64 + lane;
    float* base = zloc + (size_t)b * 32768 + i;
    float vb[32];
    #pragma unroll
    for (int j = 0; j < 32; ++j) vb[j] = base[(size_t)(w * 32 + j) * 256];
    float t = 0.f;
    #pragma unroll
    for (int j = 0; j < 32; ++j) t += vb[j];
    tot[w][lane][0] = t;
    __syncthreads();
    float r = 0.f;
    for (int w2 = 0; w2 < w; ++w2) r += tot[w2][lane][0];
    #pragma unroll
    for (int j = 0; j < 32; ++j) {
      float tt = vb[j];
      base[(size_t)(w * 32 + j) * 256] = r;
      r += tt;
    }
  }
}

// ---- k_out (R12 config, unchanged — measured 41.5us) -----------------------
// spT overlay chain: omega -> phiQ[t][i] -> phiK[tau][i] -> SpT[d][i].
__global__ __launch_bounds__(256)
__attribute__((amdgpu_waves_per_eu(1, 3))) void k_out(
    const void* __restrict__ q, const bf16* __restrict__ omb,
    const bf16* __restrict__ phiK, const void* __restrict__ v,
    const bf16* __restrict__ SlocT, const float* __restrict__ zloc,
    void* __restrict__ outp, const int* __restrict__ flag) {
  __shared__ short spT[64 * 264];   // omega -> phiQ -> phiK -> SpT
  __shared__ short vTh[64 * 72];    // V^T bf16              9216 B
  __shared__ short aT[64 * 72];     // masked A[t][tau]      9216 B

  int isf32 = *flag;
  int chunk = blockIdx.x;
  size_t tok0 = (size_t)chunk * 64;
  int tid = threadIdx.x;
  int lane = tid & 63;
  int li = lane & 15;
  int quad = lane >> 4;
  int w = __builtin_amdgcn_readfirstlane(tid >> 6);  // wave id = m-tile
  int m0 = w * 16;

  // ---- stage omega -> spT region (swizzled [256][64]) + V^T ----------------
  stage_omb_lds(omb, spT, tid);
  #pragma unroll
  for (int it = 0; it < 16; ++it) {
    int e = it * 256 + tid;
    int tau = e >> 6, d = e & 63;
    vTh[d * 72 + tau] = tob(ldin(v, tok0 * 64 + e, isf32));
  }
  // ---- zero own above-diagonal A region (rows wave-private) ----------------
  {
    shortx4 z4 = {0, 0, 0, 0};
    int arow0 = m0 + li;
    for (int cc = (w + 1) * 16 + quad * 4; cc < 64; cc += 16)
      *reinterpret_cast<shortx4*>(&aT[arow0 * 72 + cc]) = z4;
  }
  short8 qa0, qa1;
  phi_load_a(q, tok0 + m0 + li, quad, isf32, qa0, qa1);

  __syncthreads();   // BAR_A: omega LDS ready

  // ---- phase 1: phiQ (B-frags from LDS) ------------------------------------
  floatx4 c[16];
  float mx[4];
  phi_mfma_lds(spT, li, quad, qa0, qa1, c, mx);

  __syncthreads();   // BAR_B: all waves done reading omega -> reuse spT

  // ---- exp -> phiQ bits into spT own rows + den partials -------------------
  float dpart[4] = {0.f, 0.f, 0.f, 0.f};
  {
    const float* zp = zloc + (size_t)chunk * 256;
    #pragma unroll
    for (int n0 = 0; n0 < 16; ++n0) {
      float zv = zp[n0 * 16 + li];
      #pragma unroll
      for (int r = 0; r < 4; ++r) {
        bf16 hv = f2b(__expf(c[n0][r] - mx[r]) * 0.0625f);  // 1/sqrt(256)
        short hb = *reinterpret_cast<short*>(&hv);
        spT[(m0 + quad * 4 + r) * 264 + n0 * 16 + li] = hb;  // own rows only
        dpart[r] += bflo((unsigned)(unsigned short)hb) * zv; // rounded bits
      }
    }
  }

  // ---- a1-frags from own pqs rows (no barrier: wave-private) ---------------
  const short* pqf = &spT[(m0 + li) * 264 + quad * 8];
  short8 a1[8];
  #pragma unroll
  for (int kk = 0; kk < 8; ++kk)
    a1[kk] = *reinterpret_cast<const short8*>(pqf + kk * 32);

  __syncthreads();   // BAR_C: all waves done with pqs -> safe to overwrite spT

  // ---- stage phiK chunk -> spT (coalesced 16B burst) -----------------------
  {
    const short* src = (const short*)phiK + tok0 * 256;
    #pragma unroll
    for (int it = 0; it < 8; ++it) {
      int e = it * 256 + tid;
      int tau = e >> 5, seg = e & 31;
      *reinterpret_cast<short8*>(&spT[tau * 264 + seg * 8]) =
          *reinterpret_cast<const short8*>(src + tau * 256 + seg * 8);
    }
  }

  __syncthreads();   // BAR_C2: phiK tile staged

  // ---- mm1: A tiles, n0 <= w only; B-frags from LDS ------------------------
  floatx4 c1[4];
  #pragma unroll
  for (int n0 = 0; n0 < 4; ++n0) c1[n0] = (floatx4){0.f, 0.f, 0.f, 0.f};
  #pragma unroll
  for (int n0 = 0; n0 < 4; ++n0) {
    if (n0 <= w) {
      const short* bp = &spT[(n0 * 16 + li) * 264 + quad * 8];
      floatx4 acc = c1[n0];
      #pragma unroll
      for (int kk = 0; kk < 8; ++kk) {
        short8 b = *reinterpret_cast<const short8*>(bp + kk * 32);
        acc = __builtin_amdgcn_mfma_f32_16x16x32_bf16(a1[kk], b, acc, 0, 0, 0);
      }
      c1[n0] = acc;
    }
  }

  // ---- tril mask + den rowsum partials + write bf16 A to own LDS rows ------
  #pragma unroll
  for (int n0 = 0; n0 < 4; ++n0) {
    if (n0 <= w) {
      int tau = n0 * 16 + li;
      #pragma unroll
      for (int r = 0; r < 4; ++r) {
        int t = m0 + quad * 4 + r;
        float val = (tau <= t) ? c1[n0][r] : 0.f;
        dpart[r] += val;
        bf16 hh = f2b(val);
        aT[t * 72 + tau] = *reinterpret_cast<short*>(&hh);
      }
    }
  }

  __syncthreads();   // BAR_D: all waves done reading phiK tile

  // ---- re-stage spT with Sp (coalesced 16B burst) --------------------------
  {
    const short* src = (const short*)SlocT + (size_t)chunk * 16384;
    #pragma unroll
    for (int it = 0; it < 8; ++it) {
      int e = it * 256 + tid;
      int d = e >> 5, seg = e & 31;
      *reinterpret_cast<short8*>(&spT[d * 264 + seg * 8]) =
          *reinterpret_cast<const short8*>(src + d * 256 + seg * 8);
    }
  }

  __syncthreads();   // BAR_E: SpT staged, vTh ready (aT is wave-private)

  // ---- mm2 (phiQ @ Sp) + mm3 (trilA @ V), shared acc -----------------------
  floatx4 o[4];
  #pragma unroll
  for (int n0 = 0; n0 < 4; ++n0) o[n0] = (floatx4){0.f, 0.f, 0.f, 0.f};

  const short* arow = &aT[(m0 + li) * 72 + quad * 8];
  short8 a3_0 = *reinterpret_cast<const short8*>(arow);
  short8 a3_1 = *reinterpret_cast<const short8*>(arow + 32);

  #pragma unroll
  for (int n0 = 0; n0 < 4; ++n0) {
    floatx4 acc = o[n0];
    const short* sp = &spT[(n0 * 16 + li) * 264 + quad * 8];
    #pragma unroll
    for (int kk = 0; kk < 8; ++kk) {
      short8 b = *reinterpret_cast<const short8*>(sp + kk * 32);
      acc = __builtin_amdgcn_mfma_f32_16x16x32_bf16(a1[kk], b, acc, 0, 0, 0);
    }
    const short* vph = &vTh[(n0 * 16 + li) * 72 + quad * 8];
    short8 bh0 = *reinterpret_cast<const short8*>(vph);
    short8 bh1 = *reinterpret_cast<const short8*>(vph + 32);
    acc = __builtin_amdgcn_mfma_f32_16x16x32_bf16(a3_0, bh0, acc, 0, 0, 0);
    acc = __builtin_amdgcn_mfma_f32_16x16x32_bf16(a3_1, bh1, acc, 0, 0, 0);
    o[n0] = acc;
  }

  // butterfly over the quad's 16 lanes: every lane gets full den for its rows
  #pragma unroll
  for (int mask = 1; mask < 16; mask <<= 1) {
    #pragma unroll
    for (int r = 0; r < 4; ++r) dpart[r] += __shfl_xor(dpart[r], mask, 64);
  }

  // ---- epilogue: out[t][d] = (out1+out2) / (den + eps) ---------------------
  #pragma unroll
  for (int r = 0; r < 4; ++r) {
    float rd = 1.f / (dpart[r] + 1e-6f);
    size_t obb = (tok0 + m0 + quad * 4 + r) * 64 + li;
    if (isf32) {
      float* op = (float*)outp + obb;
      #pragma unroll
      for (int n0 = 0; n0 < 4; ++n0) op[n0 * 16] = o[n0][r] * rd;
    } else {
      bf16* op = (bf16*)outp + obb;
      #pragma unroll
      for (int n0 = 0; n0 < 4; ++n0) op[n0 * 16] = f2b(o[n0][r] * rd);
    }
  }
}

extern "C" void kernel_launch(void* const* d_in, const int* in_sizes, int n_in,
                              void* d_out, int out_size, void* d_ws, size_t ws_size,
                              hipStream_t stream) {
  (void)in_sizes; (void)n_in; (void)out_size;
  if (ws_size < NEED_WS_BYTES) return;   // diagnostic guard

  const void* q = d_in[0];
  const void* k = d_in[1];
  const void* v = d_in[2];
  const void* omega = d_in[3];

  int*   flag = (int*)d_ws;
  float* wsf  = (float*)d_ws + 64;       // data starts 256 B in
  bf16*  omb  = (bf16*)wsf;              // 16384 bf16
  float* zloc = wsf + 131072;            // 1024*256 f32
  bf16*  Sloc = (bf16*)(wsf + 393216);   // 1024*256*64 bf16 (TRANSPOSED [d][i])
  bf16*  phiK = (bf16*)(wsf + 17170432); // 65536*256 bf16

  k_omega<<<64, 256, 0, stream>>>(q, omega, omb, flag);
  k_phik<<<1024, 256, 0, stream>>>(k, v, omb, phiK, Sloc, zloc, flag);
  k_prefix<<<288, 256, 0, stream>>>(Sloc, zloc);
  k_out<<<1024, 256, 0, stream>>>(q, omb, phiK, v, Sloc, zloc, d_out, flag);
}

// Round 16
// 157.501 us; speedup vs baseline: 1.0307x; 1.0307x over previous
//
#include <hip/hip_runtime.h>
#include <hip/hip_bf16.h>

typedef __hip_bfloat16 bf16;
typedef __attribute__((ext_vector_type(8))) short short8;   // 8 bf16, 4 VGPRs
typedef __attribute__((ext_vector_type(4))) short shortx4;  // 4 bf16 (HIP owns "short4")
typedef __attribute__((ext_vector_type(4))) float floatx4;  // MFMA acc

// B=8, T=8192, D=64, M=256, chunk L=64, NCHUNK=1024, NTOK=65536
#define NEED_WS_BYTES 110625024ULL

__device__ __forceinline__ float b2f(bf16 x) { return __bfloat162float(x); }
__device__ __forceinline__ bf16  f2b(float x) { return __float2bfloat16(x); }
__device__ __forceinline__ float bflo(unsigned u) { return __uint_as_float(u << 16); }
__device__ __forceinline__ float bfhi(unsigned u) { return __uint_as_float(u & 0xffff0000u); }

// dtype-dispatched input load: isf32 ? f32 : bf16
__device__ __forceinline__ float ldin(const void* p, size_t i, int isf32) {
  return isf32 ? ((const float*)p)[i] : b2f(((const bf16*)p)[i]);
}

// f32 -> bf16 bits
__device__ __forceinline__ short tob(float f) {
  bf16 h = f2b(f);
  return *reinterpret_cast<short*>(&h);
}
// f32 -> bf16 bits of (f * 0.125)
__device__ __forceinline__ short sb(float f) { return tob(f * 0.125f); }
// bf16 bits -> bf16 bits of (x * 0.125) (exact exponent shift)
__device__ __forceinline__ short scale_b(short u) {
  return tob(__uint_as_float(((unsigned)(unsigned short)u) << 16) * 0.125f);
}

// inline dtype detect on q's first 8KB (R13 LESSON: run ONCE in tiny k_omega).
__device__ __forceinline__ int detect_f32(const void* q, int tid, int* cntp) {
  if (tid == 0) *cntp = 0;
  __syncthreads();
  const unsigned short* u = (const unsigned short*)q;
  int c = 0;
  for (int e = tid; e < 2048; e += 256) {
    unsigned short w = u[2 * e];
    int ex = (w >> 7) & 0xFF;
    if ((w & 0x7FFF) != 0 && (ex < 110 || ex > 140)) c++;
  }
  atomicAdd(cntp, c);
  __syncthreads();
  return (*cntp > 512) ? 1 : 0;
}

// ---- k_omega: detect + omega->bf16 buffer; block 0 publishes flag ----------
__global__ __launch_bounds__(256) void k_omega(const void* __restrict__ q,
                                               const void* __restrict__ omega,
                                               bf16* __restrict__ omb,
                                               int* __restrict__ flag) {
  __shared__ int cnt;
  int tid = threadIdx.x;
  int isf32 = detect_f32(q, tid, &cnt);
  if (blockIdx.x == 0 && tid == 0) *flag = isf32;
  int e = blockIdx.x * 256 + tid;
  omb[e] = f2b(ldin(omega, e, isf32));
}

// ---- shared phi helpers ----------------------------------------------------
// Layouts (m89/m91-verified): A[m=lane&15][k=quad*8+j], B[n=lane&15][k=quad*8+j],
// C: col=lane&15 (n-dim), row=quad*4+reg (m-dim).
__device__ __forceinline__ void phi_load_a(const void* src, size_t row, int quad,
                                           int isf32, short8& a0, short8& a1) {
  if (isf32) {
    const float* xr = (const float*)src + row * 64;
    float4 f0 = *reinterpret_cast<const float4*>(xr + quad * 8);
    float4 f1 = *reinterpret_cast<const float4*>(xr + quad * 8 + 4);
    float4 f2 = *reinterpret_cast<const float4*>(xr + 32 + quad * 8);
    float4 f3 = *reinterpret_cast<const float4*>(xr + 32 + quad * 8 + 4);
    a0[0] = sb(f0.x); a0[1] = sb(f0.y); a0[2] = sb(f0.z); a0[3] = sb(f0.w);
    a0[4] = sb(f1.x); a0[5] = sb(f1.y); a0[6] = sb(f1.z); a0[7] = sb(f1.w);
    a1[0] = sb(f2.x); a1[1] = sb(f2.y); a1[2] = sb(f2.z); a1[3] = sb(f2.w);
    a1[4] = sb(f3.x); a1[5] = sb(f3.y); a1[6] = sb(f3.z); a1[7] = sb(f3.w);
  } else {
    const short* xr = (const short*)src + row * 64;
    short8 r0 = *reinterpret_cast<const short8*>(xr + quad * 8);
    short8 r1 = *reinterpret_cast<const short8*>(xr + 32 + quad * 8);
    #pragma unroll
    for (int j = 0; j < 8; ++j) { a0[j] = scale_b(r0[j]); a1[j] = scale_b(r1[j]); }
  }
}

// ---- omega staged in LDS [256 rows][8 segs of 16B], XOR-swizzled -----------
__device__ __forceinline__ void stage_omb_lds(const bf16* __restrict__ omb,
                                              short* __restrict__ lds, int tid) {
  const short* src = (const short*)omb;
  #pragma unroll
  for (int it = 0; it < 8; ++it) {
    int seg = it * 256 + tid;          // [0,2048)
    int row = seg >> 3, s = seg & 7;
    *reinterpret_cast<short8*>(&lds[row * 64 + (s ^ (row & 7)) * 8]) =
        *reinterpret_cast<const short8*>(src + row * 64 + s * 8);
  }
}

// phi MFMA with B-frags from swizzled LDS omega (bit-identical values).
__device__ __forceinline__ void phi_mfma_lds(const short* __restrict__ oml,
                                             int li, int quad,
                                             const short8& a0, const short8& a1,
                                             floatx4* c, float* mx) {
  int x = li & 7;
  #pragma unroll
  for (int n0 = 0; n0 < 16; ++n0) {
    const short* rp = oml + (n0 * 16 + li) * 64;
    short8 b0 = *reinterpret_cast<const short8*>(rp + (quad ^ x) * 8);
    short8 b1 = *reinterpret_cast<const short8*>(rp + ((quad + 4) ^ x) * 8);
    floatx4 acc = {0.f, 0.f, 0.f, 0.f};
    acc = __builtin_amdgcn_mfma_f32_16x16x32_bf16(a0, b0, acc, 0, 0, 0);
    acc = __builtin_amdgcn_mfma_f32_16x16x32_bf16(a1, b1, acc, 0, 0, 0);
    c[n0] = acc;
  }
  #pragma unroll
  for (int r = 0; r < 4; ++r) {
    float m = c[0][r];
    #pragma unroll
    for (int n0 = 1; n0 < 16; ++n0) m = fmaxf(m, c[n0][r]);
    mx[r] = m;
  }
  #pragma unroll
  for (int mask = 1; mask < 16; mask <<= 1) {
    #pragma unroll
    for (int r = 0; r < 4; ++r) mx[r] = fmaxf(mx[r], __shfl_xor(mx[r], mask, 64));
  }
}

// ---- k_phik (R14 config — measured 42.8us) ---------------------------------
__global__ __launch_bounds__(256)
__attribute__((amdgpu_waves_per_eu(1, 4))) void k_phik(
    const void* __restrict__ k, const void* __restrict__ v,
    const bf16* __restrict__ omb, bf16* __restrict__ phiK,
    bf16* __restrict__ SlocT, float* __restrict__ zloc,
    const int* __restrict__ flag) {
  __shared__ short pkT[256 * 64];    // 32768 B  omega (phase 1) -> phiK^T
  __shared__ short vT[64 * 64];      //  8192 B  V^T bf16, XOR-swizzled

  int isf32 = *flag;
  int tid = threadIdx.x;
  size_t tok0 = (size_t)blockIdx.x * 64;
  int li = tid & 15;
  int quad = (tid >> 4) & 3;
  int w = tid >> 6;
  int m0 = w * 16;
  size_t row = tok0 + m0 + li;

  // ---- stage omega -> pkT region + V^T (bf16, swizzled) --------------------
  stage_omb_lds(omb, pkT, tid);
  #pragma unroll
  for (int it = 0; it < 16; ++it) {
    int e = it * 256 + tid;
    int tau = e >> 6, d = e & 63;
    vT[d * 64 + (((tau >> 3) ^ (d & 7)) * 8) + (tau & 7)] =
        tob(ldin(v, tok0 * 64 + e, isf32));
  }
  short8 a0, a1;
  phi_load_a(k, row, quad, isf32, a0, a1);

  __syncthreads();   // BAR_A: omega LDS ready

  // ---- phi compute (B-frags from LDS) --------------------------------------
  floatx4 c[16];
  float mx[4];
  phi_mfma_lds(pkT, li, quad, a0, a1, c, mx);

  __syncthreads();   // BAR_B: all waves done reading omega -> reuse as pkT

  // ---- exp -> phiK global scatter + swizzled pkT ---------------------------
  #pragma unroll
  for (int n0 = 0; n0 < 16; ++n0) {
    #pragma unroll
    for (int r = 0; r < 4; ++r) {
      bf16 hv = f2b(__expf(c[n0][r] - mx[r]) * 0.0625f);  // 1/sqrt(256)
      short hb = *reinterpret_cast<short*>(&hv);
      int i = n0 * 16 + li;
      int t = m0 + quad * 4 + r;
      ((short*)phiK)[(tok0 + t) * 256 + i] = hb;            // 4x32B segs/instr
      int cch = (t >> 3) ^ (i & 7);                         // XOR chunk swizzle
      pkT[i * 64 + cch * 8 + (t & 7)] = hb;
    }
  }

  __syncthreads();   // BAR_C: pkT ready

  // ---- z[i] = rowsum of pkT row i (same rounded values) --------------------
  {
    int i2 = tid;
    float zz = 0.f;
    #pragma unroll
    for (int c8 = 0; c8 < 8; ++c8) {
      short8 vv8 = *reinterpret_cast<const short8*>(
          &pkT[i2 * 64 + (c8 ^ (i2 & 7)) * 8]);
      #pragma unroll
      for (int j = 0; j < 8; ++j) zz += bflo((unsigned)(unsigned short)vv8[j]);
    }
    zloc[(size_t)blockIdx.x * 256 + i2] = zz;
  }

  // ---- S GEMM (bf16 V): wave w -> features [w*64, w*64+64), all d ----------
  int wbase = w * 64;
  floatx4 sa[4][4];
  #pragma unroll
  for (int mt = 0; mt < 4; ++mt)
    #pragma unroll
    for (int n0 = 0; n0 < 4; ++n0) sa[mt][n0] = (floatx4){0.f, 0.f, 0.f, 0.f};

  #pragma unroll
  for (int h = 0; h < 2; ++h) {
    short8 Ah[4];
    #pragma unroll
    for (int mt = 0; mt < 4; ++mt)
      Ah[mt] = *reinterpret_cast<const short8*>(
          &vT[(mt * 16 + li) * 64 + ((h * 4 + quad) ^ (li & 7)) * 8]);
    #pragma unroll
    for (int n0 = 0; n0 < 4; ++n0) {
      int crow = wbase + n0 * 16 + li;
      int cc = (h * 4 + quad) ^ (li & 7);
      short8 Bq = *reinterpret_cast<const short8*>(&pkT[crow * 64 + cc * 8]);
      #pragma unroll
      for (int mt = 0; mt < 4; ++mt)
        sa[mt][n0] =
            __builtin_amdgcn_mfma_f32_16x16x32_bf16(Ah[mt], Bq, sa[mt][n0], 0, 0, 0);
    }
  }

  // ---- store S^T (bf16) ----------------------------------------------------
  bf16* Sb = SlocT + (size_t)blockIdx.x * 16384;
  #pragma unroll
  for (int mt = 0; mt < 4; ++mt)
    #pragma unroll
    for (int n0 = 0; n0 < 4; ++n0)
      #pragma unroll
      for (int r = 0; r < 4; ++r)
        Sb[(mt * 16 + quad * 4 + r) * 256 + wbase + n0 * 16 + li] =
            f2b(sa[mt][n0][r]);
}

// ---- k_prefix (R14 short2/1056-block version — best measured) --------------
// R15 LESSON: uint4 widening cut the grid 1024->256 blocks (16->4 waves/CU);
// at 32KB access stride this kernel lives on outstanding-request COUNT, not
// per-request width. Reverted.
__global__ __launch_bounds__(256) void k_prefix(bf16* __restrict__ SlocT,
                                                float* __restrict__ zloc) {
  __shared__ float tot[4][64][2];
  int tid = threadIdx.x;
  int lane = tid & 63;
  int w = tid >> 6;
  if (blockIdx.x < 1024) {
    int b = blockIdx.x >> 7, g = blockIdx.x & 127;
    int p = g * 64 + lane;                    // short2 column [0,8192)
    unsigned* base = (unsigned*)(SlocT + (size_t)b * 2097152) + p;
    unsigned vb[32];
    #pragma unroll
    for (int j = 0; j < 32; ++j) vb[j] = base[(size_t)(w * 32 + j) * 8192];
    float t0 = 0.f, t1 = 0.f;
    #pragma unroll
    for (int j = 0; j < 32; ++j) { t0 += bflo(vb[j]); t1 += bfhi(vb[j]); }
    tot[w][lane][0] = t0; tot[w][lane][1] = t1;
    __syncthreads();
    float r0 = 0.f, r1 = 0.f;
    for (int w2 = 0; w2 < w; ++w2) {          // wave-uniform trip count
      r0 += tot[w2][lane][0]; r1 += tot[w2][lane][1];
    }
    #pragma unroll
    for (int j = 0; j < 32; ++j) {
      unsigned u = vb[j];
      bf16 h0 = f2b(r0), h1 = f2b(r1);
      unsigned pw = ((unsigned)*(unsigned short*)&h0) |
                    (((unsigned)*(unsigned short*)&h1) << 16);
      base[(size_t)(w * 32 + j) * 8192] = pw;
      r0 += bflo(u); r1 += bfhi(u);
    }
  } else {
    int idx = blockIdx.x - 1024;              // [0,32)
    int b = idx >> 2, ig = idx & 3;
    int i = ig * 64 + lane;
    float* base = zloc + (size_t)b * 32768 + i;
    float vb[32];
    #pragma unroll
    for (int j = 0; j < 32; ++j) vb[j] = base[(size_t)(w * 32 + j) * 256];
    float t = 0.f;
    #pragma unroll
    for (int j = 0; j < 32; ++j) t += vb[j];
    tot[w][lane][0] = t;
    __syncthreads();
    float r = 0.f;
    for (int w2 = 0; w2 < w; ++w2) r += tot[w2][lane][0];
    #pragma unroll
    for (int j = 0; j < 32; ++j) {
      float tt = vb[j];
      base[(size_t)(w * 32 + j) * 256] = r;
      r += tt;
    }
  }
}

// ---- k_out (R12 config — measured 41.5us) ----------------------------------
// spT overlay chain: omega -> phiQ[t][i] -> phiK[tau][i] -> SpT[d][i].
__global__ __launch_bounds__(256)
__attribute__((amdgpu_waves_per_eu(1, 3))) void k_out(
    const void* __restrict__ q, const bf16* __restrict__ omb,
    const bf16* __restrict__ phiK, const void* __restrict__ v,
    const bf16* __restrict__ SlocT, const float* __restrict__ zloc,
    void* __restrict__ outp, const int* __restrict__ flag) {
  __shared__ short spT[64 * 264];   // omega -> phiQ -> phiK -> SpT
  __shared__ short vTh[64 * 72];    // V^T bf16              9216 B
  __shared__ short aT[64 * 72];     // masked A[t][tau]      9216 B

  int isf32 = *flag;
  int chunk = blockIdx.x;
  size_t tok0 = (size_t)chunk * 64;
  int tid = threadIdx.x;
  int lane = tid & 63;
  int li = lane & 15;
  int quad = lane >> 4;
  int w = __builtin_amdgcn_readfirstlane(tid >> 6);  // wave id = m-tile
  int m0 = w * 16;

  // ---- stage omega -> spT region (swizzled [256][64]) + V^T ----------------
  stage_omb_lds(omb, spT, tid);
  #pragma unroll
  for (int it = 0; it < 16; ++it) {
    int e = it * 256 + tid;
    int tau = e >> 6, d = e & 63;
    vTh[d * 72 + tau] = tob(ldin(v, tok0 * 64 + e, isf32));
  }
  // ---- zero own above-diagonal A region (rows wave-private) ----------------
  {
    shortx4 z4 = {0, 0, 0, 0};
    int arow0 = m0 + li;
    for (int cc = (w + 1) * 16 + quad * 4; cc < 64; cc += 16)
      *reinterpret_cast<shortx4*>(&aT[arow0 * 72 + cc]) = z4;
  }
  short8 qa0, qa1;
  phi_load_a(q, tok0 + m0 + li, quad, isf32, qa0, qa1);

  __syncthreads();   // BAR_A: omega LDS ready

  // ---- phase 1: phiQ (B-frags from LDS) ------------------------------------
  floatx4 c[16];
  float mx[4];
  phi_mfma_lds(spT, li, quad, qa0, qa1, c, mx);

  __syncthreads();   // BAR_B: all waves done reading omega -> reuse spT

  // ---- exp -> phiQ bits into spT own rows + den partials -------------------
  float dpart[4] = {0.f, 0.f, 0.f, 0.f};
  {
    const float* zp = zloc + (size_t)chunk * 256;
    #pragma unroll
    for (int n0 = 0; n0 < 16; ++n0) {
      float zv = zp[n0 * 16 + li];
      #pragma unroll
      for (int r = 0; r < 4; ++r) {
        bf16 hv = f2b(__expf(c[n0][r] - mx[r]) * 0.0625f);  // 1/sqrt(256)
        short hb = *reinterpret_cast<short*>(&hv);
        spT[(m0 + quad * 4 + r) * 264 + n0 * 16 + li] = hb;  // own rows only
        dpart[r] += bflo((unsigned)(unsigned short)hb) * zv; // rounded bits
      }
    }
  }

  // ---- a1-frags from own pqs rows (no barrier: wave-private) ---------------
  const short* pqf = &spT[(m0 + li) * 264 + quad * 8];
  short8 a1[8];
  #pragma unroll
  for (int kk = 0; kk < 8; ++kk)
    a1[kk] = *reinterpret_cast<const short8*>(pqf + kk * 32);

  __syncthreads();   // BAR_C: all waves done with pqs -> safe to overwrite spT

  // ---- stage phiK chunk -> spT (coalesced 16B burst) -----------------------
  {
    const short* src = (const short*)phiK + tok0 * 256;
    #pragma unroll
    for (int it = 0; it < 8; ++it) {
      int e = it * 256 + tid;
      int tau = e >> 5, seg = e & 31;
      *reinterpret_cast<short8*>(&spT[tau * 264 + seg * 8]) =
          *reinterpret_cast<const short8*>(src + tau * 256 + seg * 8);
    }
  }

  __syncthreads();   // BAR_C2: phiK tile staged

  // ---- mm1: A tiles, n0 <= w only; B-frags from LDS ------------------------
  floatx4 c1[4];
  #pragma unroll
  for (int n0 = 0; n0 < 4; ++n0) c1[n0] = (floatx4){0.f, 0.f, 0.f, 0.f};
  #pragma unroll
  for (int n0 = 0; n0 < 4; ++n0) {
    if (n0 <= w) {
      const short* bp = &spT[(n0 * 16 + li) * 264 + quad * 8];
      floatx4 acc = c1[n0];
      #pragma unroll
      for (int kk = 0; kk < 8; ++kk) {
        short8 b = *reinterpret_cast<const short8*>(bp + kk * 32);
        acc = __builtin_amdgcn_mfma_f32_16x16x32_bf16(a1[kk], b, acc, 0, 0, 0);
      }
      c1[n0] = acc;
    }
  }

  // ---- tril mask + den rowsum partials + write bf16 A to own LDS rows ------
  #pragma unroll
  for (int n0 = 0; n0 < 4; ++n0) {
    if (n0 <= w) {
      int tau = n0 * 16 + li;
      #pragma unroll
      for (int r = 0; r < 4; ++r) {
        int t = m0 + quad * 4 + r;
        float val = (tau <= t) ? c1[n0][r] : 0.f;
        dpart[r] += val;
        bf16 hh = f2b(val);
        aT[t * 72 + tau] = *reinterpret_cast<short*>(&hh);
      }
    }
  }

  __syncthreads();   // BAR_D: all waves done reading phiK tile

  // ---- re-stage spT with Sp (coalesced 16B burst) --------------------------
  {
    const short* src = (const short*)SlocT + (size_t)chunk * 16384;
    #pragma unroll
    for (int it = 0; it < 8; ++it) {
      int e = it * 256 + tid;
      int d = e >> 5, seg = e & 31;
      *reinterpret_cast<short8*>(&spT[d * 264 + seg * 8]) =
          *reinterpret_cast<const short8*>(src + d * 256 + seg * 8);
    }
  }

  __syncthreads();   // BAR_E: SpT staged, vTh ready (aT is wave-private)

  // ---- mm2 (phiQ @ Sp) + mm3 (trilA @ V), shared acc -----------------------
  floatx4 o[4];
  #pragma unroll
  for (int n0 = 0; n0 < 4; ++n0) o[n0] = (floatx4){0.f, 0.f, 0.f, 0.f};

  const short* arow = &aT[(m0 + li) * 72 + quad * 8];
  short8 a3_0 = *reinterpret_cast<const short8*>(arow);
  short8 a3_1 = *reinterpret_cast<const short8*>(arow + 32);

  #pragma unroll
  for (int n0 = 0; n0 < 4; ++n0) {
    floatx4 acc = o[n0];
    const short* sp = &spT[(n0 * 16 + li) * 264 + quad * 8];
    #pragma unroll
    for (int kk = 0; kk < 8; ++kk) {
      short8 b = *reinterpret_cast<const short8*>(sp + kk * 32);
      acc = __builtin_amdgcn_mfma_f32_16x16x32_bf16(a1[kk], b, acc, 0, 0, 0);
    }
    const short* vph = &vTh[(n0 * 16 + li) * 72 + quad * 8];
    short8 bh0 = *reinterpret_cast<const short8*>(vph);
    short8 bh1 = *reinterpret_cast<const short8*>(vph + 32);
    acc = __builtin_amdgcn_mfma_f32_16x16x32_bf16(a3_0, bh0, acc, 0, 0, 0);
    acc = __builtin_amdgcn_mfma_f32_16x16x32_bf16(a3_1, bh1, acc, 0, 0, 0);
    o[n0] = acc;
  }

  // butterfly over the quad's 16 lanes: every lane gets full den for its rows
  #pragma unroll
  for (int mask = 1; mask < 16; mask <<= 1) {
    #pragma unroll
    for (int r = 0; r < 4; ++r) dpart[r] += __shfl_xor(dpart[r], mask, 64);
  }

  // ---- epilogue: out[t][d] = (out1+out2) / (den + eps) ---------------------
  #pragma unroll
  for (int r = 0; r < 4; ++r) {
    float rd = 1.f / (dpart[r] + 1e-6f);
    size_t obb = (tok0 + m0 + quad * 4 + r) * 64 + li;
    if (isf32) {
      float* op = (float*)outp + obb;
      #pragma unroll
      for (int n0 = 0; n0 < 4; ++n0) op[n0 * 16] = o[n0][r] * rd;
    } else {
      bf16* op = (bf16*)outp + obb;
      #pragma unroll
      for (int n0 = 0; n0 < 4; ++n0) op[n0 * 16] = f2b(o[n0][r] * rd);
    }
  }
}

extern "C" void kernel_launch(void* const* d_in, const int* in_sizes, int n_in,
                              void* d_out, int out_size, void* d_ws, size_t ws_size,
                              hipStream_t stream) {
  (void)in_sizes; (void)n_in; (void)out_size;
  if (ws_size < NEED_WS_BYTES) return;   // diagnostic guard

  const void* q = d_in[0];
  const void* k = d_in[1];
  const void* v = d_in[2];
  const void* omega = d_in[3];

  int*   flag = (int*)d_ws;
  float* wsf  = (float*)d_ws + 64;       // data starts 256 B in
  bf16*  omb  = (bf16*)wsf;              // 16384 bf16
  float* zloc = wsf + 131072;            // 1024*256 f32
  bf16*  Sloc = (bf16*)(wsf + 393216);   // 1024*256*64 bf16 (TRANSPOSED [d][i])
  bf16*  phiK = (bf16*)(wsf + 17170432); // 65536*256 bf16

  k_omega<<<64, 256, 0, stream>>>(q, omega, omb, flag);
  k_phik<<<1024, 256, 0, stream>>>(k, v, omb, phiK, Sloc, zloc, flag);
  k_prefix<<<1056, 256, 0, stream>>>(Sloc, zloc);
  k_out<<<1024, 256, 0, stream>>>(q, omb, phiK, v, Sloc, zloc, d_out, flag);
}